// Round 9
// baseline (3472.648 us; speedup 1.0000x reference)
//
#include <hip/hip_runtime.h>
#include <hip/hip_bf16.h>

// Correctness contract (exact path verified absmax=0 through R8):
//   xc   = sequential __fmaf_rn chain over d=0..63 ascending
//   x2,c2= numpy pairwise scalar 8-accumulator scheme
//   dist = fl(fl(x2 - 2*xc) + c2), argmin first-occurrence
//
// R-this-round (fp16 fast pass + in-loop candidate capture):
//   R8 post-mortem: 650us was pass-2 (40% flag rate at bf16's eps, per-lane
//   H64 candidate capture vs lane-local min, 128KB L2 re-stream per group;
//   VALUBusy 27%x650=175us). Fix:
//   - fp16 (u=2^-11): eps <= 4u*sqrt(x2*c2); M = 8e-3*sqrt(x2*c2max)+0.05
//     >= 2*eps with 2x slack -> flag rate ~11%, ~1 true candidate each.
//   - candidate bits {k: s <= v1_run + M} captured DURING the main pass
//     (3 VALU per chain-g; tc compile-time via full unroll). Superset of
//     {s <= v1_final + 2eps} which contains the exact argmin + all exact
//     ties (s_k* <= v1_final + 2eps <= v1_run + M at visit time).
//   - flagged tokens resolved in-place in the merge loop: the 16 owner
//     lanes exact-eval their own captured bits (bit-exact fp32 chain,
//     ascending k per lane, lex-(val,k) butterfly = first-occurrence).
//     NO re-pass, no flag queue. c2max computed in prep (global atomicMax).
//   Main loop: 4 MFMA + 2 ds_read per tile; skeleton = R3 measured-best
//   (16 phases x 4 tiles dbuf, 2048 x 256thr, launch_bounds(256,4)).
#pragma clang fp contract(off)

#define NSUB 16
#define CBK  1024
#define SDIM 64
#define EMB  1024
#define NTOK 16384
#define TOKB 128
#define MCOEF  8e-3f
#define MFLOOR 0.05f

typedef __attribute__((ext_vector_type(8))) _Float16 f16x8;
typedef __attribute__((ext_vector_type(4))) float f32x4;

__device__ __forceinline__ float fmul(float a, float b) { return __fmul_rn(a, b); }
__device__ __forceinline__ float fadd(float a, float b) { return __fadd_rn(a, b); }
__device__ __forceinline__ float fsub(float a, float b) { return __fsub_rn(a, b); }

// numpy pairwise replica (scalar 8-accumulator, n=64), contiguous.
__device__ __forceinline__ float np_sq64(const float* v) {
    float r[8];
    #pragma unroll
    for (int j = 0; j < 8; ++j) r[j] = fmul(v[j], v[j]);
    #pragma unroll
    for (int b = 1; b < 8; ++b) {
        #pragma unroll
        for (int j = 0; j < 8; ++j)
            r[j] = fadd(r[j], fmul(v[b * 8 + j], v[b * 8 + j]));
    }
    return fadd(fadd(fadd(r[0], r[1]), fadd(r[2], r[3])),
                fadd(fadd(r[4], r[5]), fadd(r[6], r[7])));
}

// async global->LDS, 16B per lane; dest = wave-uniform base + lane*16.
typedef const __attribute__((address_space(1))) unsigned int gu32;
typedef __attribute__((address_space(3))) unsigned int lu32;
__device__ __forceinline__ void stage16(const void* g, void* l) {
    __builtin_amdgcn_global_load_lds((gu32*)g, (lu32*)l, 16, 0, 0);
}

// ---- prep: pack fp16(-2*codebook) into MFMA B-fragment layout + C2 + c2max ----
// bpack layout: [m][tc=64][c=2][lane=64][j=8] fp16  (2 MB)
__global__ __launch_bounds__(256)
void prep_kernel(const float* __restrict__ cb,
                 unsigned short* __restrict__ bpack,
                 float* __restrict__ c2g,
                 int* __restrict__ c2maxg)
{
    const int bx = blockIdx.x;   // 0..31
    const int m  = blockIdx.y;   // 0..15
    const int t  = threadIdx.x;
    const int w  = t >> 6, l = t & 63;
    const int tc = bx * 2 + (w & 1);           // tile-col 0..63
    const int c  = w >> 1;                     // c-half 0..1
    const int cw = tc * 16 + (l & 15);
    const int dq = (l >> 4) * 8;

    {
        const float* src = cb + ((size_t)m * CBK + cw) * SDIM + c * 32 + dq;
        f16x8 hv;
        #pragma unroll
        for (int j = 0; j < 8; ++j)
            hv[j] = (_Float16)(-2.0f * src[j]);  // -2x exact in fp32, then RN
        size_t base = (((size_t)(m * 64 + tc) * 2 + c)) * 512 + (size_t)l * 8;
        *(f16x8*)(bpack + base) = hv;            // 16B vector stores, coalesced
    }
    if (t < 32) {
        const int row = bx * 32 + t;
        const float c2 = np_sq64(cb + ((size_t)m * CBK + row) * SDIM);
        c2g[m * CBK + row] = c2;
        atomicMax(&c2maxg[m], __float_as_int(c2));   // c2 > 0: int-order == float-order
    }
}

// ---- transpose: ws indices [m][NTOK] -> iout [NTOK][16], full-line writes ----
__global__ __launch_bounds__(256)
void idx_transpose_kernel(const float* __restrict__ iws,
                          float* __restrict__ iout)
{
    const int tok = blockIdx.x * 256 + threadIdx.x;
    float v[NSUB];
    #pragma unroll
    for (int m = 0; m < NSUB; ++m)
        v[m] = iws[(size_t)m * NTOK + tok];      // coalesced per-m reads
    float* dst = iout + (size_t)tok * NSUB;      // 64B line per thread
    #pragma unroll
    for (int c = 0; c < 4; ++c)
        *(f32x4*)(dst + c * 4) = *(f32x4*)(v + c * 4);
}

// ---- main: fp16 fast pass, in-loop candidate capture, in-place exact rescue ----
__global__ __launch_bounds__(256, 4)
void pq_mfma_kernel(const float* __restrict__ emb,
                    const float* __restrict__ cb,
                    const unsigned short* __restrict__ bpack,
                    const float* __restrict__ c2g,
                    const int* __restrict__ c2maxg,
                    float* __restrict__ qout,
                    float* __restrict__ iws)
{
    __shared__ __align__(16) unsigned short bs[2][4 * 1024];  // 2 x 8KB B stage
    __shared__ float C2s[CBK];              // 4 KB replica ||c||^2
    __shared__ float x2s[TOKB];             // per-token ||x||^2 (margin input)
    __shared__ int   bestk_s[TOKB];

    // XCD-aware decomposition: XCD (rank%8) only sees m in {rank%8, rank%8+8}
    const int rank = blockIdx.x;
    const int m    = rank & 15;
    const int tok0 = (rank >> 4) * TOKB;

    const int t = threadIdx.x, w = t >> 6, l = t & 63;
    const int ln15 = l & 15, q = l >> 4;

    *(f32x4*)(C2s + t * 4) = *(const f32x4*)(c2g + m * CBK + t * 4);

    const unsigned short* gB = bpack + (size_t)m * 64 * 1024;  // 128KB slice

    // stage phase 0 (tiles 0..3, 8KB)
    {
        const unsigned short* src = gB + t * 8;
        #pragma unroll
        for (int j = 0; j < 2; ++j)
            stage16(src + j * 2048, &bs[0][j * 2048 + t * 8]);
    }

    // x fragments (A-operand: row=lane&15, k=(lane>>4)*8+j), fp16 RN;
    // per-token x2 partial (16 dims/lane) -> xor-reduce over q-lanes.
    f16x8 xh[2][2];
    #pragma unroll
    for (int r = 0; r < 2; ++r) {
        const int tok = tok0 + w * 32 + r * 16 + ln15;
        float x2p = 0.f;
        #pragma unroll
        for (int c = 0; c < 2; ++c) {
            const float* src = emb + (size_t)tok * EMB + m * SDIM + c * 32 + q * 8;
            float4 v0 = *(const float4*)(src);
            float4 v1 = *(const float4*)(src + 4);
            float vv[8] = {v0.x,v0.y,v0.z,v0.w,v1.x,v1.y,v1.z,v1.w};
            #pragma unroll
            for (int j = 0; j < 8; ++j) {
                xh[r][c][j] = (_Float16)vv[j];
                x2p += vv[j] * vv[j];
            }
        }
        x2p += __shfl_xor(x2p, 16);
        x2p += __shfl_xor(x2p, 32);
        if (l < 16) x2s[w * 32 + r * 16 + l] = x2p;   // lane q==0 writes
    }

    float v1t[2][4], v2t[2][4]; int k1t[2][4];
    unsigned int cml[2][4], cmh[2][4];                // captured candidate bits
    #pragma unroll
    for (int r = 0; r < 2; ++r)
        #pragma unroll
        for (int g = 0; g < 4; ++g) {
            v1t[r][g] = 3.4e38f; v2t[r][g] = 3.4e38f; k1t[r][g] = 0;
            cml[r][g] = 0u; cmh[r][g] = 0u;
        }

    __syncthreads();   // C2s/x2s visible + phase-0 stage complete

    // per-lane margins for the tokens this lane's acc rows belong to
    const float c2mx = __int_as_float(c2maxg[m]);
    float Mr[2][4];
    #pragma unroll
    for (int r = 0; r < 2; ++r)
        #pragma unroll
        for (int g = 0; g < 4; ++g)
            Mr[r][g] = MCOEF * sqrtf(x2s[w * 32 + r * 16 + q * 4 + g] * c2mx) + MFLOOR;

    // 16 phases x 4 tiles (fully unrolled: tc literal -> 1-instr mask update).
    #pragma unroll
    for (int ph = 0; ph < 16; ++ph) {
        const int buf = ph & 1;
        if (ph < 15) {
            const unsigned short* src = gB + (ph + 1) * 4096 + t * 8;
            #pragma unroll
            for (int j = 0; j < 2; ++j)
                stage16(src + j * 2048, &bs[buf ^ 1][j * 2048 + t * 8]);
        }
        #pragma unroll
        for (int j = 0; j < 4; ++j) {
            const int tc = ph * 4 + j;
            const unsigned short* bp = &bs[buf][j * 1024 + l * 8];
            f16x8 B0 = *(const f16x8*)(bp);
            f16x8 B1 = *(const f16x8*)(bp + 512);
            const int kk = tc * 16 + ln15;
            const float c2v = C2s[kk];
            f32x4 a0 = {c2v, c2v, c2v, c2v};
            f32x4 a1 = {c2v, c2v, c2v, c2v};
            a0 = __builtin_amdgcn_mfma_f32_16x16x32_f16(xh[0][0], B0, a0, 0, 0, 0);
            a1 = __builtin_amdgcn_mfma_f32_16x16x32_f16(xh[1][0], B0, a1, 0, 0, 0);
            a0 = __builtin_amdgcn_mfma_f32_16x16x32_f16(xh[0][1], B1, a0, 0, 0, 0);
            a1 = __builtin_amdgcn_mfma_f32_16x16x32_f16(xh[1][1], B1, a1, 0, 0, 0);
            #pragma unroll
            for (int g = 0; g < 4; ++g) {
                float s0 = a0[g];
                // capture BEFORE update: v1_run(pre) >= v1_final -> superset
                bool p0 = s0 <= v1t[0][g] + Mr[0][g];
                if (tc < 32) cml[0][g] |= p0 ? (1u << tc) : 0u;
                else         cmh[0][g] |= p0 ? (1u << (tc - 32)) : 0u;
                v2t[0][g] = fminf(v2t[0][g], fmaxf(s0, v1t[0][g]));
                bool lt0 = s0 < v1t[0][g];
                v1t[0][g] = lt0 ? s0 : v1t[0][g];
                k1t[0][g] = lt0 ? kk : k1t[0][g];

                float s1 = a1[g];
                bool p1 = s1 <= v1t[1][g] + Mr[1][g];
                if (tc < 32) cml[1][g] |= p1 ? (1u << tc) : 0u;
                else         cmh[1][g] |= p1 ? (1u << (tc - 32)) : 0u;
                v2t[1][g] = fminf(v2t[1][g], fmaxf(s1, v1t[1][g]));
                bool lt1 = s1 < v1t[1][g];
                v1t[1][g] = lt1 ? s1 : v1t[1][g];
                k1t[1][g] = lt1 ? kk : k1t[1][g];
            }
        }
        __syncthreads();
    }

    // merge top-2 across the 16 lanes sharing each token (C/D row = q*4+g);
    // near-ties resolved in-place by the same 16 lanes from captured bits.
    #pragma unroll
    for (int r = 0; r < 2; ++r) {
        #pragma unroll
        for (int g = 0; g < 4; ++g) {
            float v1 = v1t[r][g], v2 = v2t[r][g]; int k1 = k1t[r][g];
            #pragma unroll
            for (int mask = 1; mask < 16; mask <<= 1) {
                float ov1 = __shfl_xor(v1, mask);
                float ov2 = __shfl_xor(v2, mask);
                int   ok1 = __shfl_xor(k1, mask);
                if (ov1 < v1 || (ov1 == v1 && ok1 < k1)) {
                    v2 = fminf(v1, ov2);
                    v1 = ov1; k1 = ok1;
                } else {
                    v2 = fminf(v2, ov1);
                }
            }
            const int token = w * 32 + r * 16 + q * 4 + g;
            if (v2 - v1 > Mr[r][g]) {
                // unambiguous: for all k', d_k' - d_k1 >= (v2-v1) - 2eps > 0
                if (ln15 == 0) {
                    bestk_s[token] = k1;
                    iws[(size_t)m * NTOK + tok0 + token] = (float)k1;
                }
            } else {
                // exact rescue: each lane evaluates its own captured bits
                const float* xrow = emb + (size_t)(tok0 + token) * EMB + m * SDIM;
                const float x2v = np_sq64(xrow);          // broadcast reads
                unsigned long long msk =
                    ((unsigned long long)cmh[r][g] << 32) | cml[r][g];
                float bv = 3.4e38f; int bk = CBK;
                while (msk) {
                    const int tc = __builtin_ctzll(msk);
                    msk &= msk - 1;                       // ascending k per lane
                    const int k = tc * 16 + ln15;
                    const float* crow = cb + ((size_t)m * CBK + k) * SDIM;
                    float acc = 0.f;
                    #pragma unroll
                    for (int i = 0; i < 16; ++i) {
                        float4 c4 = *(const float4*)(crow + 4 * i);
                        float4 x4 = *(const float4*)(xrow + 4 * i);
                        acc = __fmaf_rn(x4.x, c4.x, acc);
                        acc = __fmaf_rn(x4.y, c4.y, acc);
                        acc = __fmaf_rn(x4.z, c4.z, acc);
                        acc = __fmaf_rn(x4.w, c4.w, acc);
                    }
                    const float dist = fadd(fsub(x2v, fmul(2.f, acc)), C2s[k]);
                    if (dist < bv) { bv = dist; bk = k; } // strict < keeps smallest k
                }
                // (val,k)-lexicographic min across the 16 owner lanes
                #pragma unroll
                for (int mask = 1; mask < 16; mask <<= 1) {
                    float ov = __shfl_xor(bv, mask);
                    int   ok = __shfl_xor(bk, mask);
                    if (ov < bv || (ov == bv && ok < bk)) { bv = ov; bk = ok; }
                }
                if (ln15 == 0) {
                    bestk_s[token] = bk;
                    iws[(size_t)m * NTOK + tok0 + token] = (float)bk;
                }
            }
        }
    }
    __syncthreads();

    // ---- gather winning codewords ----
    {
        const int tok = t >> 1, d0 = (t & 1) * 32;
        const int bk  = bestk_s[tok];
        const float* src = cb + ((size_t)m * CBK + bk) * SDIM + d0;
        float* dst = qout + (size_t)(tok0 + tok) * EMB + m * SDIM + d0;
        #pragma unroll
        for (int i = 0; i < 8; ++i)
            *(float4*)(dst + 4 * i) = *(const float4*)(src + 4 * i);
    }
}

extern "C" void kernel_launch(void* const* d_in, const int* in_sizes, int n_in,
                              void* d_out, int out_size, void* d_ws, size_t ws_size,
                              hipStream_t stream) {
    const float* emb = (const float*)d_in[0];   // [8,2048,1024] f32
    const float* cb  = (const float*)d_in[1];   // [16,1024,64] f32
    float* qout = (float*)d_out;                              // [N, EMB] f32
    float* iout = (float*)d_out + (size_t)NTOK * EMB;         // [N, 16] as f32

    unsigned short* bpack = (unsigned short*)d_ws;                         // 2 MB
    float* c2g = (float*)((char*)d_ws + 2u * 1024u * 1024u);               // 64 KB
    float* iws = (float*)((char*)d_ws + 2u * 1024u * 1024u + 64u * 1024u); // 1 MB
    int* c2maxg = (int*)((char*)d_ws + 3u * 1024u * 1024u + 64u * 1024u);  // 64 B

    hipMemsetAsync(c2maxg, 0, NSUB * sizeof(int), stream);
    prep_kernel<<<dim3(32, 16), 256, 0, stream>>>(cb, bpack, c2g, c2maxg);
    pq_mfma_kernel<<<dim3(NTOK / TOKB * NSUB), 256, 0, stream>>>(
        emb, cb, bpack, c2g, c2maxg, qout, iws);
    idx_transpose_kernel<<<dim3(NTOK / 256), 256, 0, stream>>>(iws, iout);
}